// Round 1
// 206.769 us; speedup vs baseline: 1.0862x; 1.0862x over previous
//
#include <hip/hip_runtime.h>
#include <hip/hip_bf16.h>
#include <math.h>

typedef __bf16 bf16t;
typedef __bf16 bf8v __attribute__((ext_vector_type(8)));
typedef float  f4v  __attribute__((ext_vector_type(4)));

#define DD  4
#define FF  64
#define HH  128
#define FIN 129
#define MT  128   // rows per block

#define AS1 __attribute__((address_space(1)))
#define AS3 __attribute__((address_space(3)))

// XOR-swizzled LDS index: element [row][k] of a row-major [*][128] bf16 tile,
// 16B chunk (k>>3) XORed with (row&7) -> conflict-free ds_read_b128 at pitch 128.
__device__ __forceinline__ int swz(int row, int k) {
  return row * HH + ((((k >> 3) ^ (row & 7)) << 3) | (k & 7));
}

// ---- weight prep: f32 -> bf16, transposed to [n][k] for B-fragment loads ----
__global__ void prep_weights(const float* __restrict__ w1,
                             const float* __restrict__ w2,
                             const float* __restrict__ w3,
                             bf16t* __restrict__ w1t,
                             bf16t* __restrict__ w2t,
                             bf16t* __restrict__ w3t,
                             float* __restrict__ w1last) {
  int i = blockIdx.x * blockDim.x + threadIdx.x;
  if (i < DD * HH * HH) {            // 65536: w1t + w2t
    int d = i >> 14, n = (i >> 7) & 127, k = i & 127;
    w1t[i] = (bf16t)w1[(d * FIN + k) * HH + n];
    w2t[i] = (bf16t)w2[(d * HH + k) * HH + n];
  }
  if (i < HH * HH) {                 // 16384: w3t
    int n = i >> 7, k = i & 127;
    w3t[i] = (bf16t)w3[k * HH + n];
  }
  if (i < DD * HH) {                 // 512: last feat column of w1, kept f32
    int d = i >> 7, n = i & 127;
    w1last[i] = w1[(d * FIN + 128) * HH + n];
  }
}

// Async stage of a 128x128 bf16 [n][k] tile into swizzled ldsW via
// global_load_lds (width 16). LDS dest is LINEAR (chunk = tid + j*256,
// wave-uniform base + lane*16); the XOR swizzle is applied to the GLOBAL
// source chunk instead (rule: both-sides-or-neither). Since 256 chunks/step
// = 16 rows and 16 % 8 == 0, the permutation g0 is j-invariant: source
// address is just base + j*4096 bytes. Completion is drained by the
// vmcnt(0) that __syncthreads() emits.
__device__ __forceinline__ void stage_w_async(const bf16t* __restrict__ w,
                                              bf16t* __restrict__ ldsW,
                                              int tid, int wave) {
  int g0 = (tid & ~15) | ((tid & 15) ^ ((tid >> 4) & 7));
  const bf16t* src = w + g0 * 8;            // 16B source chunk (permuted)
  bf16t* dst = ldsW + wave * 64 * 8;        // wave-uniform 16B-chunk base
  #pragma unroll
  for (int j = 0; j < 8; ++j) {
    __builtin_amdgcn_global_load_lds((const AS1 void*)(src + j * 2048),
                                     (AS3 void*)(dst + j * 2048), 16, 0, 0);
  }
}

__launch_bounds__(256, 2)
__global__ void fourier_mlp(
    const float* __restrict__ cont,   // [N,4]
    const float* __restrict__ freqs,  // [4,64]
    const float* __restrict__ b1,     // [4,128]
    const float* __restrict__ ln1g,
    const float* __restrict__ ln1b,
    const float* __restrict__ b2,
    const float* __restrict__ outg,   // [128]
    const float* __restrict__ outb,
    const float* __restrict__ b3,
    const bf16t* __restrict__ w1t,    // [4][128][128] bf16, [d][n][k]
    const bf16t* __restrict__ w2t,    // [4][128][128]
    const bf16t* __restrict__ w3t,    // [128][128]
    const float* __restrict__ w1last, // [4][128]
    float* __restrict__ out)          // [N,128] f32
{
  __shared__ __align__(16) bf16t ldsA[MT * HH];  // 32 KB: h / emb tiles
  __shared__ __align__(16) bf16t ldsW[HH * HH];  // 32 KB: current weight

  const int tid   = threadIdx.x;
  const int lane  = tid & 63;
  const int wave  = tid >> 6;
  const int q     = lane >> 4;
  const int l15   = lane & 15;
  const int rowbase = blockIdx.x * MT;
  const int wrow  = wave * 32;     // wave's 32-row slab in the block tile

  const f4v fzero = {0.0f, 0.0f, 0.0f, 0.0f};

  f4v emb[2][8];
  #pragma unroll
  for (int rt = 0; rt < 2; ++rt)
    #pragma unroll
    for (int nt = 0; nt < 8; ++nt) emb[rt][nt] = fzero;

  for (int d = 0; d < DD; ++d) {
    __syncthreads();  // prior iter's GEMM2 reads of ldsW complete
    stage_w_async(w1t + d * HH * HH, ldsW, tid, wave);

    // loads that overlap the w1 staging latency
    const float c0 = cont[(rowbase + wrow + l15) * DD + d];
    const float c1 = cont[(rowbase + wrow + 16 + l15) * DD + d];
    __syncthreads();  // w1 in LDS (syncthreads drains vmcnt)

    // ---- GEMM1 with on-the-fly Fourier features (A-fragments in regs) ----
    // A-frag for (row wrow+l15 / +16, k = kk + q*8 + u): k<64 -> cos(c*f[k]),
    // k>=64 -> sin(c*f[k-64]); angle t = fract(c*f) shared by cos & sin pass.
    f4v acc[2][8];
    #pragma unroll
    for (int rt = 0; rt < 2; ++rt)
      #pragma unroll
      for (int nt = 0; nt < 8; ++nt) acc[rt][nt] = fzero;

    #pragma unroll
    for (int hf = 0; hf < 2; ++hf) {       // freq half: k-base hf*32
      float fr[8];
      *(f4v*)&fr[0] = *(const f4v*)&freqs[d * FF + hf * 32 + q * 8];
      *(f4v*)&fr[4] = *(const f4v*)&freqs[d * FF + hf * 32 + q * 8 + 4];
      float t0[8], t1[8];
      #pragma unroll
      for (int u = 0; u < 8; ++u) {
        float a = c0 * fr[u]; t0[u] = a - floorf(a);   // revolutions
        float b = c1 * fr[u]; t1[u] = b - floorf(b);
      }
      #pragma unroll
      for (int tr = 0; tr < 2; ++tr) {     // 0: cos block, 1: sin block (+64)
        bf8v a0, a1;
        #pragma unroll
        for (int u = 0; u < 8; ++u) {
          a0[u] = (bf16t)(tr ? __builtin_amdgcn_sinf(t0[u])
                             : __builtin_amdgcn_cosf(t0[u]));
          a1[u] = (bf16t)(tr ? __builtin_amdgcn_sinf(t1[u])
                             : __builtin_amdgcn_cosf(t1[u]));
        }
        const int kk = tr * 64 + hf * 32;
        #pragma unroll
        for (int nt = 0; nt < 8; ++nt) {
          bf8v b = *(const bf8v*)&ldsW[swz(nt * 16 + l15, kk + q * 8)];
          acc[0][nt] = __builtin_amdgcn_mfma_f32_16x16x32_bf16(a0, b, acc[0][nt], 0, 0, 0);
          acc[1][nt] = __builtin_amdgcn_mfma_f32_16x16x32_bf16(a1, b, acc[1][nt], 0, 0, 0);
        }
      }
    }

    __syncthreads();  // all waves done with w1 reads in ldsW
    stage_w_async(w2t + d * HH * HH, ldsW, tid, wave);  // hides under epilogue

    // ---- epilogue: + b1 + rank-1 (f32 exact), LayerNorm, ReLU -> ldsA ----
    float w1l[8], b1v[8], gv[8], bv[8];
    #pragma unroll
    for (int nt = 0; nt < 8; ++nt) {
      int n = nt * 16 + l15;
      w1l[nt] = w1last[d * HH + n];
      b1v[nt] = b1[d * HH + n];
      gv[nt]  = ln1g[d * HH + n];
      bv[nt]  = ln1b[d * HH + n];
    }
    #pragma unroll
    for (int rt = 0; rt < 2; ++rt) {
      float cv[4], s[4], ss[4];
      #pragma unroll
      for (int r = 0; r < 4; ++r) {
        cv[r] = cont[(rowbase + wrow + rt * 16 + q * 4 + r) * DD + d];
        s[r] = 0.0f; ss[r] = 0.0f;
      }
      #pragma unroll
      for (int nt = 0; nt < 8; ++nt)
        #pragma unroll
        for (int r = 0; r < 4; ++r) {
          float v = acc[rt][nt][r] + b1v[nt] + cv[r] * w1l[nt];
          acc[rt][nt][r] = v;
          s[r] += v; ss[r] += v * v;
        }
      #pragma unroll
      for (int m = 1; m < 16; m <<= 1)
        #pragma unroll
        for (int r = 0; r < 4; ++r) {
          s[r]  += __shfl_xor(s[r],  m);
          ss[r] += __shfl_xor(ss[r], m);
        }
      #pragma unroll
      for (int r = 0; r < 4; ++r) {
        float mu   = s[r] * (1.0f / 128.0f);
        float var  = ss[r] * (1.0f / 128.0f) - mu * mu;
        float rstd = rsqrtf(var + 1e-5f);
        int mrow = wrow + rt * 16 + q * 4 + r;
        #pragma unroll
        for (int nt = 0; nt < 8; ++nt) {
          float v = (acc[rt][nt][r] - mu) * rstd * gv[nt] + bv[nt];
          v = fmaxf(v, 0.0f);
          // own slab: no cross-wave hazard, barrier-free write
          ldsA[swz(mrow, nt * 16 + l15)] = (bf16t)v;
        }
      }
    }
    __syncthreads();  // w2 in LDS

    // ---- GEMM2: emb += h_relu @ w2 ----
    #pragma unroll
    for (int kk = 0; kk < 128; kk += 32) {
      bf8v a0 = *(const bf8v*)&ldsA[swz(wrow + l15,      kk + q * 8)];
      bf8v a1 = *(const bf8v*)&ldsA[swz(wrow + 16 + l15, kk + q * 8)];
      #pragma unroll
      for (int nt = 0; nt < 8; ++nt) {
        bf8v b = *(const bf8v*)&ldsW[swz(nt * 16 + l15, kk + q * 8)];
        emb[0][nt] = __builtin_amdgcn_mfma_f32_16x16x32_bf16(a0, b, emb[0][nt], 0, 0, 0);
        emb[1][nt] = __builtin_amdgcn_mfma_f32_16x16x32_bf16(a1, b, emb[1][nt], 0, 0, 0);
      }
    }
    // + b2[d]
    #pragma unroll
    for (int nt = 0; nt < 8; ++nt) {
      float b2v = b2[d * HH + nt * 16 + l15];
      #pragma unroll
      for (int rt = 0; rt < 2; ++rt)
        #pragma unroll
        for (int r = 0; r < 4; ++r) emb[rt][nt][r] += b2v;
    }
  } // d loop

  __syncthreads();  // all waves done with w2 reads
  stage_w_async(w3t, ldsW, tid, wave);  // hides under final LN

  // ---- final LayerNorm + ReLU on emb -> ldsA (bf16) ----
  {
    float gv[8], bv[8];
    #pragma unroll
    for (int nt = 0; nt < 8; ++nt) {
      gv[nt] = outg[nt * 16 + l15];
      bv[nt] = outb[nt * 16 + l15];
    }
    #pragma unroll
    for (int rt = 0; rt < 2; ++rt) {
      float s[4], ss[4];
      #pragma unroll
      for (int r = 0; r < 4; ++r) { s[r] = 0.0f; ss[r] = 0.0f; }
      #pragma unroll
      for (int nt = 0; nt < 8; ++nt)
        #pragma unroll
        for (int r = 0; r < 4; ++r) {
          float v = emb[rt][nt][r];
          s[r] += v; ss[r] += v * v;
        }
      #pragma unroll
      for (int m = 1; m < 16; m <<= 1)
        #pragma unroll
        for (int r = 0; r < 4; ++r) {
          s[r]  += __shfl_xor(s[r],  m);
          ss[r] += __shfl_xor(ss[r], m);
        }
      #pragma unroll
      for (int r = 0; r < 4; ++r) {
        float mu   = s[r] * (1.0f / 128.0f);
        float var  = ss[r] * (1.0f / 128.0f) - mu * mu;
        float rstd = rsqrtf(var + 1e-5f);
        int mrow = wrow + rt * 16 + q * 4 + r;
        #pragma unroll
        for (int nt = 0; nt < 8; ++nt) {
          float v = (emb[rt][nt][r] - mu) * rstd * gv[nt] + bv[nt];
          v = fmaxf(v, 0.0f);
          ldsA[swz(mrow, nt * 16 + l15)] = (bf16t)v;
        }
      }
    }
  }
  __syncthreads();  // w3 in LDS

  // ---- GEMM3: out = ln_relu(emb) @ w3 + b3 ----
  f4v acc[2][8];
  {
    const f4v z = {0.0f, 0.0f, 0.0f, 0.0f};
    #pragma unroll
    for (int rt = 0; rt < 2; ++rt)
      #pragma unroll
      for (int nt = 0; nt < 8; ++nt) acc[rt][nt] = z;
  }
  #pragma unroll
  for (int kk = 0; kk < 128; kk += 32) {
    bf8v a0 = *(const bf8v*)&ldsA[swz(wrow + l15,      kk + q * 8)];
    bf8v a1 = *(const bf8v*)&ldsA[swz(wrow + 16 + l15, kk + q * 8)];
    #pragma unroll
    for (int nt = 0; nt < 8; ++nt) {
      bf8v b = *(const bf8v*)&ldsW[swz(nt * 16 + l15, kk + q * 8)];
      acc[0][nt] = __builtin_amdgcn_mfma_f32_16x16x32_bf16(a0, b, acc[0][nt], 0, 0, 0);
      acc[1][nt] = __builtin_amdgcn_mfma_f32_16x16x32_bf16(a1, b, acc[1][nt], 0, 0, 0);
    }
  }
  #pragma unroll
  for (int nt = 0; nt < 8; ++nt) {
    float b3v = b3[nt * 16 + l15];
    #pragma unroll
    for (int rt = 0; rt < 2; ++rt)
      #pragma unroll
      for (int r = 0; r < 4; ++r)
        out[(rowbase + wrow + rt * 16 + q * 4 + r) * HH + nt * 16 + l15] =
            acc[rt][nt][r] + b3v;
  }
}

extern "C" void kernel_launch(void* const* d_in, const int* in_sizes, int n_in,
                              void* d_out, int out_size, void* d_ws, size_t ws_size,
                              hipStream_t stream) {
  const float* cont  = (const float*)d_in[0];
  const float* freqs = (const float*)d_in[1];
  const float* w1    = (const float*)d_in[2];
  const float* b1    = (const float*)d_in[3];
  const float* ln1g  = (const float*)d_in[4];
  const float* ln1b  = (const float*)d_in[5];
  const float* w2    = (const float*)d_in[6];
  const float* b2    = (const float*)d_in[7];
  const float* outg  = (const float*)d_in[8];
  const float* outb  = (const float*)d_in[9];
  const float* w3    = (const float*)d_in[10];
  const float* b3    = (const float*)d_in[11];
  float* out = (float*)d_out;

  // ws layout: w1t[65536] bf16 | w2t[65536] bf16 | w3t[16384] bf16 | w1last[512] f32
  bf16t* w1t = (bf16t*)d_ws;
  bf16t* w2t = w1t + DD * HH * HH;
  bf16t* w3t = w2t + DD * HH * HH;
  float* w1last = (float*)((char*)d_ws + (2 * DD * HH * HH + HH * HH) * sizeof(bf16t));

  prep_weights<<<(DD * HH * HH + 255) / 256, 256, 0, stream>>>(
      w1, w2, w3, w1t, w2t, w3t, w1last);

  int n_rows = in_sizes[0] / DD;       // 131072
  int grid = n_rows / MT;              // 1024
  fourier_mlp<<<grid, 256, 0, stream>>>(
      cont, freqs, b1, ln1g, ln1b, b2, outg, outb, b3,
      w1t, w2t, w3t, w1last, out);
}